// Round 1
// baseline (98.356 us; speedup 1.0000x reference)
//
#include <hip/hip_runtime.h>
#include <cstddef>
#include <cmath>

#define NB 8
#define NP 30000
#define NS 9
#define NC 64          // in channels
#define NO 64          // out channels

typedef __bf16 bf16x8 __attribute__((ext_vector_type(8)));
typedef unsigned short u16x8 __attribute__((ext_vector_type(8)));
typedef float f32x4 __attribute__((ext_vector_type(4)));

__device__ __forceinline__ unsigned short f2bf(float f) {
  unsigned int u = __float_as_uint(f);
  u += 0x7FFFu + ((u >> 16) & 1u);   // round-to-nearest-even
  return (unsigned short)(u >> 16);
}

// --- prep: W (64 x 576) fp32 -> bf16 B-fragment layout in ws ---
// frag id = (s*2 + kh)*4 + ct ; within frag: lane*8 + j  (contiguous 16B per lane)
// value = W[ct*16 + (lane&15)][s*64 + kh*32 + (lane>>4)*8 + j]
__global__ void prep_w_kernel(const float* __restrict__ W, unsigned short* __restrict__ wf) {
  int t = blockIdx.x * 256 + threadIdx.x;
  if (t >= NS * 2 * 4 * 64) return;
  int lane = t & 63;
  int ct = (t >> 6) & 3;
  int kh = (t >> 8) & 1;
  int s  = t >> 9;
  int col = ct * 16 + (lane & 15);
  int kb  = s * 64 + kh * 32 + ((lane >> 4) << 3);
  u16x8 v;
#pragma unroll
  for (int j = 0; j < 8; ++j) v[j] = f2bf(W[col * 576 + kb + j]);
  *(u16x8*)&wf[t * 8] = v;
}

template<bool PREPPED>
__global__ __launch_bounds__(256) void spiral_mfma(
    const float* __restrict__ x, const void* __restrict__ adj_raw,
    const float* __restrict__ W, const float* __restrict__ bias,
    const unsigned short* __restrict__ wf, float* __restrict__ out) {
  __shared__ unsigned short Alds[64][72];   // row stride 144 B (16B mult; 2-way banks only)
  __shared__ int idx_lds[NS][64];

  const int tid = threadIdx.x;
  const int b  = blockIdx.y;
  const int n0 = blockIdx.x * 64;

  // spiral_adj may arrive as int32 or int64; int64 (values < 2^31) has all
  // odd 32-bit words == 0. Uniform, data-driven, deterministic detection.
  const int* a32 = (const int*)adj_raw;
  const long long* a64 = (const long long*)adj_raw;
  const bool is64 = ((a32[1] | a32[3] | a32[5] | a32[7]) == 0);

  for (int i = tid; i < 64 * NS; i += 256) {
    int r = i / NS, s = i - r * NS;
    int n = n0 + r;
    int v = 0;
    if (n < NP) {
      size_t pos = ((size_t)b * NP + n) * NS + s;
      long long vv = is64 ? a64[pos] : (long long)a32[pos];
      v = (int)vv;
      if ((unsigned)v >= (unsigned)NP) v = 0;  // safety clamp
    }
    idx_lds[s][r] = v;
  }

  const int w = tid >> 6;
  const int l = tid & 63;
  const int grow  = tid >> 2;      // gather row 0..63 (4 threads per row)
  const int gpart = tid & 3;       // each thread: 16 channels

  f32x4 acc[4] = {};

  __syncthreads();

  for (int s = 0; s < NS; ++s) {
    // B fragments for this s (registers; same addresses across waves -> L1 hits)
    bf16x8 bfr[4][2];
    if (PREPPED) {
      const uint4* wfp = (const uint4*)wf;
#pragma unroll
      for (int ct = 0; ct < 4; ++ct)
#pragma unroll
        for (int kh = 0; kh < 2; ++kh) {
          int fid = (s * 2 + kh) * 4 + ct;
          uint4 v = wfp[fid * 64 + l];
          bfr[ct][kh] = __builtin_bit_cast(bf16x8, v);
        }
    } else {
#pragma unroll
      for (int ct = 0; ct < 4; ++ct)
#pragma unroll
        for (int kh = 0; kh < 2; ++kh) {
          int col = ct * 16 + (l & 15);
          int kb  = s * 64 + kh * 32 + ((l >> 4) << 3);
          const float4* wp = (const float4*)&W[col * 576 + kb];
          float4 w0 = wp[0], w1 = wp[1];
          u16x8 t;
          t[0] = f2bf(w0.x); t[1] = f2bf(w0.y); t[2] = f2bf(w0.z); t[3] = f2bf(w0.w);
          t[4] = f2bf(w1.x); t[5] = f2bf(w1.y); t[6] = f2bf(w1.z); t[7] = f2bf(w1.w);
          bfr[ct][kh] = __builtin_bit_cast(bf16x8, t);
        }
    }

    // gather A tile: 64 rows x 64 ch, fp32 -> bf16 on the fly
    {
      int idx = idx_lds[s][grow];
      const float4* src = (const float4*)(x + ((size_t)b * NP + idx) * NC + gpart * 16);
      float4 f0 = src[0], f1 = src[1], f2 = src[2], f3 = src[3];
      u16x8 t0, t1;
      t0[0] = f2bf(f0.x); t0[1] = f2bf(f0.y); t0[2] = f2bf(f0.z); t0[3] = f2bf(f0.w);
      t0[4] = f2bf(f1.x); t0[5] = f2bf(f1.y); t0[6] = f2bf(f1.z); t0[7] = f2bf(f1.w);
      t1[0] = f2bf(f2.x); t1[1] = f2bf(f2.y); t1[2] = f2bf(f2.z); t1[3] = f2bf(f2.w);
      t1[4] = f2bf(f3.x); t1[5] = f2bf(f3.y); t1[6] = f2bf(f3.z); t1[7] = f2bf(f3.w);
      *(u16x8*)&Alds[grow][gpart * 16]     = t0;
      *(u16x8*)&Alds[grow][gpart * 16 + 8] = t1;
    }
    __syncthreads();

    const int arow = w * 16 + (l & 15);
    const int kc   = (l >> 4) << 3;
    bf16x8 a0 = *(const bf16x8*)&Alds[arow][kc];
    bf16x8 a1 = *(const bf16x8*)&Alds[arow][32 + kc];
#pragma unroll
    for (int ct = 0; ct < 4; ++ct) {
      acc[ct] = __builtin_amdgcn_mfma_f32_16x16x32_bf16(a0, bfr[ct][0], acc[ct], 0, 0, 0);
      acc[ct] = __builtin_amdgcn_mfma_f32_16x16x32_bf16(a1, bfr[ct][1], acc[ct], 0, 0, 0);
    }
    __syncthreads();
  }

  // epilogue: bias + ELU + pad-vertex mask + store
  // D layout (verified m89): col = lane&15, row = (lane>>4)*4 + reg
  const int orow0 = w * 16 + ((l >> 4) << 2);
#pragma unroll
  for (int ct = 0; ct < 4; ++ct) {
    int col = ct * 16 + (l & 15);
    float bv = bias[col];
#pragma unroll
    for (int r = 0; r < 4; ++r) {
      int n = n0 + orow0 + r;
      if (n < NP) {
        float v = acc[ct][r] + bv;
        v = (v > 0.f) ? v : expm1f(v);
        if (n == NP - 1) v = 0.f;
        out[((size_t)b * NP + n) * NO + col] = v;
      }
    }
  }
}

extern "C" void kernel_launch(void* const* d_in, const int* in_sizes, int n_in,
                              void* d_out, int out_size, void* d_ws, size_t ws_size,
                              hipStream_t stream) {
  const float* x    = (const float*)d_in[0];
  // d_in[1] = t_vertex (unused by the reference computation)
  const void*  adj  = d_in[2];
  const float* W    = (const float*)d_in[3];
  const float* bias = (const float*)d_in[4];
  float* out = (float*)d_out;

  dim3 grid((NP + 63) / 64, NB);
  if (ws_size >= (size_t)(NS * 2 * 4 * 64 * 8 * 2)) {  // 73728 B
    unsigned short* wfrag = (unsigned short*)d_ws;
    prep_w_kernel<<<18, 256, 0, stream>>>(W, wfrag);
    spiral_mfma<true><<<grid, 256, 0, stream>>>(x, adj, W, bias, wfrag, out);
  } else {
    spiral_mfma<false><<<grid, 256, 0, stream>>>(x, adj, W, bias, nullptr, out);
  }
}

// Round 2
// 92.809 us; speedup vs baseline: 1.0598x; 1.0598x over previous
//
#include <hip/hip_runtime.h>
#include <cstddef>
#include <cmath>

#define NB 8
#define NP 30000
#define NS 9
#define NC 64          // in channels
#define NO 64          // out channels

typedef __bf16 bf16x8 __attribute__((ext_vector_type(8)));
typedef unsigned short u16x8 __attribute__((ext_vector_type(8)));
typedef float f32x4 __attribute__((ext_vector_type(4)));

__device__ __forceinline__ unsigned short f2bf(float f) {
  unsigned int u = __float_as_uint(f);
  u += 0x7FFFu + ((u >> 16) & 1u);   // round-to-nearest-even
  return (unsigned short)(u >> 16);
}

// --- prep: W (64 x 576) fp32 -> bf16 B-fragment layout in ws ---
// frag id = (s*2 + kh)*4 + ct ; within frag: lane*8 + j  (contiguous 16B per lane)
// value = W[ct*16 + (lane&15)][s*64 + kh*32 + (lane>>4)*8 + j]
__global__ void prep_w_kernel(const float* __restrict__ W, unsigned short* __restrict__ wf) {
  int t = blockIdx.x * 256 + threadIdx.x;
  if (t >= NS * 2 * 4 * 64) return;
  int lane = t & 63;
  int ct = (t >> 6) & 3;
  int kh = (t >> 8) & 1;
  int s  = t >> 9;
  int col = ct * 16 + (lane & 15);
  int kb  = s * 64 + kh * 32 + ((lane >> 4) << 3);
  u16x8 v;
#pragma unroll
  for (int j = 0; j < 8; ++j) v[j] = f2bf(W[col * 576 + kb + j]);
  *(u16x8*)&wf[t * 8] = v;
}

// --- prep: x fp32 -> bf16 (halves gather bytes; per-batch slice fits 4MB XCD L2) ---
__global__ __launch_bounds__(256) void prep_x_kernel(const float* __restrict__ x,
                                                     unsigned short* __restrict__ xh) {
  size_t i = ((size_t)blockIdx.x * 256 + threadIdx.x) * 8;
  if (i >= (size_t)NB * NP * NC) return;
  float4 f0 = *(const float4*)(x + i);
  float4 f1 = *(const float4*)(x + i + 4);
  u16x8 v;
  v[0] = f2bf(f0.x); v[1] = f2bf(f0.y); v[2] = f2bf(f0.z); v[3] = f2bf(f0.w);
  v[4] = f2bf(f1.x); v[5] = f2bf(f1.y); v[6] = f2bf(f1.z); v[7] = f2bf(f1.w);
  *(u16x8*)&xh[i] = v;
}

// Barrier-free gather-GEMM: no LDS, A-fragments gathered per-lane directly.
// 128 rows/block (2 row-tiles per wave), all 64 out cols, K=576 fully unrolled.
template<bool FULL>
__global__ __launch_bounds__(256, 4) void spiral_main(
    const float* __restrict__ x, const void* __restrict__ adj_raw,
    const float* __restrict__ W, const float* __restrict__ bias,
    const unsigned short* __restrict__ xh, const unsigned short* __restrict__ wf,
    float* __restrict__ out) {
  const int tid = threadIdx.x;
  const int bid = blockIdx.x;
  const int b    = bid & 7;     // batch -> XCD pinning (bid%8 round-robin)
  const int tile = bid >> 3;
  const int n0 = tile * 128;
  const int w  = tid >> 6;
  const int l  = tid & 63;
  const int lr = l & 15;        // A/D row-within-16, B/D col-within-16
  const int kq = l >> 4;        // k-chunk 0..3

  // spiral_adj may arrive as int32 or int64; int64 (values < 2^31) has all
  // odd 32-bit words == 0. Uniform, data-driven, deterministic detection.
  const int* a32 = (const int*)adj_raw;
  const long long* a64 = (const long long*)adj_raw;
  const bool is64 = ((a32[1] | a32[3] | a32[5] | a32[7]) == 0);

  int idx[2][NS];
#pragma unroll
  for (int rt = 0; rt < 2; ++rt) {
    int n = n0 + rt * 64 + w * 16 + lr;
    int nc = (n < NP) ? n : 0;
    size_t base = ((size_t)b * NP + nc) * NS;
#pragma unroll
    for (int s = 0; s < NS; ++s) {
      long long vv = is64 ? a64[base + s] : (long long)a32[base + s];
      int vi = (int)vv;
      idx[rt][s] = ((unsigned)vi < (unsigned)NP) ? vi : 0;
    }
  }

  f32x4 acc[2][4] = {};

  if (FULL) {
    // bf16 x, prepped W fragments. Zero barriers, zero LDS.
    const unsigned short* xb = xh + (size_t)b * NP * NC + kq * 8;
    const uint4* wfp = (const uint4*)wf;
#pragma unroll
    for (int s = 0; s < NS; ++s) {
      bf16x8 a[2][2];
#pragma unroll
      for (int rt = 0; rt < 2; ++rt) {
        const unsigned short* src = xb + (size_t)idx[rt][s] * NC;
        a[rt][0] = __builtin_bit_cast(bf16x8, *(const u16x8*)(src));
        a[rt][1] = __builtin_bit_cast(bf16x8, *(const u16x8*)(src + 32));
      }
#pragma unroll
      for (int ct = 0; ct < 4; ++ct) {
#pragma unroll
        for (int kh = 0; kh < 2; ++kh) {
          int fid = (s * 2 + kh) * 4 + ct;
          bf16x8 bf = __builtin_bit_cast(bf16x8, wfp[fid * 64 + l]);
          acc[0][ct] = __builtin_amdgcn_mfma_f32_16x16x32_bf16(a[0][kh], bf, acc[0][ct], 0, 0, 0);
          acc[1][ct] = __builtin_amdgcn_mfma_f32_16x16x32_bf16(a[1][kh], bf, acc[1][ct], 0, 0, 0);
        }
      }
    }
  } else {
    // Fallback (no workspace): fp32 gather + in-loop conversions.
    const float* xbf = x + (size_t)b * NP * NC + kq * 8;
#pragma unroll
    for (int s = 0; s < NS; ++s) {
      bf16x8 a[2][2];
#pragma unroll
      for (int rt = 0; rt < 2; ++rt) {
        const float* src = xbf + (size_t)idx[rt][s] * NC;
        float4 f0 = *(const float4*)src, f1 = *(const float4*)(src + 4);
        float4 g0 = *(const float4*)(src + 32), g1 = *(const float4*)(src + 36);
        u16x8 t0, t1;
        t0[0] = f2bf(f0.x); t0[1] = f2bf(f0.y); t0[2] = f2bf(f0.z); t0[3] = f2bf(f0.w);
        t0[4] = f2bf(f1.x); t0[5] = f2bf(f1.y); t0[6] = f2bf(f1.z); t0[7] = f2bf(f1.w);
        t1[0] = f2bf(g0.x); t1[1] = f2bf(g0.y); t1[2] = f2bf(g0.z); t1[3] = f2bf(g0.w);
        t1[4] = f2bf(g1.x); t1[5] = f2bf(g1.y); t1[6] = f2bf(g1.z); t1[7] = f2bf(g1.w);
        a[rt][0] = __builtin_bit_cast(bf16x8, t0);
        a[rt][1] = __builtin_bit_cast(bf16x8, t1);
      }
#pragma unroll
      for (int ct = 0; ct < 4; ++ct) {
#pragma unroll
        for (int kh = 0; kh < 2; ++kh) {
          int col = ct * 16 + lr;
          int kb  = s * 64 + kh * 32 + (kq << 3);
          const float4* wp = (const float4*)&W[col * 576 + kb];
          float4 w0 = wp[0], w1 = wp[1];
          u16x8 t;
          t[0] = f2bf(w0.x); t[1] = f2bf(w0.y); t[2] = f2bf(w0.z); t[3] = f2bf(w0.w);
          t[4] = f2bf(w1.x); t[5] = f2bf(w1.y); t[6] = f2bf(w1.z); t[7] = f2bf(w1.w);
          bf16x8 bf = __builtin_bit_cast(bf16x8, t);
          acc[0][ct] = __builtin_amdgcn_mfma_f32_16x16x32_bf16(a[0][kh], bf, acc[0][ct], 0, 0, 0);
          acc[1][ct] = __builtin_amdgcn_mfma_f32_16x16x32_bf16(a[1][kh], bf, acc[1][ct], 0, 0, 0);
        }
      }
    }
  }

  // epilogue: bias + ELU + pad-vertex mask + store
  // D layout (verified m89): col = lane&15, row = (lane>>4)*4 + reg
  const int orow = w * 16 + (kq << 2);
#pragma unroll
  for (int rt = 0; rt < 2; ++rt) {
#pragma unroll
    for (int ct = 0; ct < 4; ++ct) {
      int col = ct * 16 + lr;
      float bv = bias[col];
#pragma unroll
      for (int r = 0; r < 4; ++r) {
        int n = n0 + rt * 64 + orow + r;
        if (n < NP) {
          float v = acc[rt][ct][r] + bv;
          v = (v > 0.f) ? v : expm1f(v);
          if (n == NP - 1) v = 0.f;
          out[((size_t)b * NP + n) * NO + col] = v;
        }
      }
    }
  }
}

extern "C" void kernel_launch(void* const* d_in, const int* in_sizes, int n_in,
                              void* d_out, int out_size, void* d_ws, size_t ws_size,
                              hipStream_t stream) {
  const float* x    = (const float*)d_in[0];
  // d_in[1] = t_vertex (unused by the reference computation)
  const void*  adj  = d_in[2];
  const float* W    = (const float*)d_in[3];
  const float* bias = (const float*)d_in[4];
  float* out = (float*)d_out;

  const size_t wbytes = (size_t)NS * 2 * 4 * 64 * 8 * 2;        // 73728
  const size_t xbytes = (size_t)NB * NP * NC * 2;               // 30,720,000
  const int nblk = ((NP + 127) / 128) * NB;                     // 235*8 = 1880

  if (ws_size >= wbytes + xbytes) {
    unsigned short* wfrag = (unsigned short*)d_ws;
    unsigned short* xh    = (unsigned short*)((char*)d_ws + wbytes);
    prep_w_kernel<<<18, 256, 0, stream>>>(W, wfrag);
    prep_x_kernel<<<(int)((NB * NP * NC / 8 + 255) / 256), 256, 0, stream>>>(x, xh);
    spiral_main<true><<<nblk, 256, 0, stream>>>(x, adj, W, bias, xh, wfrag, out);
  } else {
    spiral_main<false><<<nblk, 256, 0, stream>>>(x, adj, W, bias, nullptr, nullptr, out);
  }
}

// Round 3
// 92.303 us; speedup vs baseline: 1.0656x; 1.0055x over previous
//
#include <hip/hip_runtime.h>
#include <cstddef>
#include <cmath>

#define NB 8
#define NP 30000
#define NS 9
#define NC 64          // in channels
#define NO 64          // out channels

typedef __bf16 bf16x8 __attribute__((ext_vector_type(8)));
typedef unsigned short u16x8 __attribute__((ext_vector_type(8)));
typedef float f32x4 __attribute__((ext_vector_type(4)));

__device__ __forceinline__ unsigned short f2bf(float f) {
  unsigned int u = __float_as_uint(f);
  u += 0x7FFFu + ((u >> 16) & 1u);   // round-to-nearest-even
  return (unsigned short)(u >> 16);
}

// --- prep: W (64 x 576) fp32 -> bf16 B-fragment layout in ws ---
// frag id = (s*2 + kh)*4 + ct ; within frag: lane*8 + j  (contiguous 16B per lane)
// value = W[ct*16 + (lane&15)][s*64 + kh*32 + (lane>>4)*8 + j]
__global__ void prep_w_kernel(const float* __restrict__ W, unsigned short* __restrict__ wf) {
  int t = blockIdx.x * 256 + threadIdx.x;
  if (t >= NS * 2 * 4 * 64) return;
  int lane = t & 63;
  int ct = (t >> 6) & 3;
  int kh = (t >> 8) & 1;
  int s  = t >> 9;
  int col = ct * 16 + (lane & 15);
  int kb  = s * 64 + kh * 32 + ((lane >> 4) << 3);
  u16x8 v;
#pragma unroll
  for (int j = 0; j < 8; ++j) v[j] = f2bf(W[col * 576 + kb + j]);
  *(u16x8*)&wf[t * 8] = v;
}

// --- prep: x fp32 -> bf16 (halves gather bytes; per-batch slice fits 4MB XCD L2) ---
__global__ __launch_bounds__(256) void prep_x_kernel(const float* __restrict__ x,
                                                     unsigned short* __restrict__ xh) {
  size_t i = ((size_t)blockIdx.x * 256 + threadIdx.x) * 8;
  if (i >= (size_t)NB * NP * NC) return;
  float4 f0 = *(const float4*)(x + i);
  float4 f1 = *(const float4*)(x + i + 4);
  u16x8 v;
  v[0] = f2bf(f0.x); v[1] = f2bf(f0.y); v[2] = f2bf(f0.z); v[3] = f2bf(f0.w);
  v[4] = f2bf(f1.x); v[5] = f2bf(f1.y); v[6] = f2bf(f1.z); v[7] = f2bf(f1.w);
  *(u16x8*)&xh[i] = v;
}

// Barrier-free gather-GEMM, explicit depth-2 software pipeline over spiral slots.
// 128 rows/block (2 row-tiles per wave), all 64 out cols, K=576 fully unrolled.
template<bool FULL>
__global__ __launch_bounds__(256, 3) void spiral_main(
    const float* __restrict__ x, const void* __restrict__ adj_raw,
    const float* __restrict__ W, const float* __restrict__ bias,
    const unsigned short* __restrict__ xh, const unsigned short* __restrict__ wf,
    float* __restrict__ out) {
  const int tid = threadIdx.x;
  const int bid = blockIdx.x;
  const int b    = bid & 7;     // batch -> XCD pinning (bid%8 round-robin)
  const int tile = bid >> 3;
  const int n0 = tile * 128;
  const int w  = tid >> 6;
  const int l  = tid & 63;
  const int lr = l & 15;        // A/D row-within-16, B/D col-within-16
  const int kq = l >> 4;        // k-chunk 0..3

  // spiral_adj may arrive as int32 or int64; int64 (values < 2^31) has all
  // odd 32-bit words == 0. Uniform, data-driven, deterministic detection.
  const int* a32 = (const int*)adj_raw;
  const long long* a64 = (const long long*)adj_raw;
  const bool is64 = ((a32[1] | a32[3] | a32[5] | a32[7]) == 0);

  int idx[2][NS];
#pragma unroll
  for (int rt = 0; rt < 2; ++rt) {
    int n = n0 + rt * 64 + w * 16 + lr;
    int nc = (n < NP) ? n : 0;
    size_t base = ((size_t)b * NP + nc) * NS;
#pragma unroll
    for (int s = 0; s < NS; ++s) {
      long long vv = is64 ? a64[base + s] : (long long)a32[base + s];
      int vi = (int)vv;
      idx[rt][s] = ((unsigned)vi < (unsigned)NP) ? vi : 0;
    }
  }

  f32x4 acc[2][4] = {};

  if (FULL) {
    // bf16 x, prepped W fragments. Zero barriers, zero LDS.
    const unsigned short* xb = xh + (size_t)b * NP * NC + kq * 8;
    const uint4* wfp = (const uint4*)wf;

    // 3-slot rotating A-fragment buffer; all indices compile-time constants
    // after full unroll (no scratch per rule #20). Depth-2 prefetch: loads for
    // s+2 are issued before the MFMAs of s, so each gather has ~2 MFMA stages
    // (x #waves interleave) to complete.
    bf16x8 abuf[3][2][2];

#define LOADA(S, SLOT)                                                        \
  {                                                                           \
    _Pragma("unroll")                                                         \
    for (int rt = 0; rt < 2; ++rt) {                                          \
      const unsigned short* src = xb + (size_t)idx[rt][(S)] * NC;             \
      abuf[(SLOT)][rt][0] = __builtin_bit_cast(bf16x8, *(const u16x8*)(src)); \
      abuf[(SLOT)][rt][1] = __builtin_bit_cast(bf16x8, *(const u16x8*)(src + 32)); \
    }                                                                         \
  }

    LOADA(0, 0);
    LOADA(1, 1);

#pragma unroll
    for (int s = 0; s < NS; ++s) {
      if (s + 2 < NS) LOADA(s + 2, (s + 2) % 3);
      // W fragments for this s — same addresses across waves/blocks -> L1 hits
      bf16x8 wv[2][4];
#pragma unroll
      for (int kh = 0; kh < 2; ++kh)
#pragma unroll
        for (int ct = 0; ct < 4; ++ct)
          wv[kh][ct] = __builtin_bit_cast(bf16x8, wfp[((s * 2 + kh) * 4 + ct) * 64 + l]);
#pragma unroll
      for (int ct = 0; ct < 4; ++ct)
#pragma unroll
        for (int kh = 0; kh < 2; ++kh) {
          acc[0][ct] = __builtin_amdgcn_mfma_f32_16x16x32_bf16(abuf[s % 3][0][kh], wv[kh][ct], acc[0][ct], 0, 0, 0);
          acc[1][ct] = __builtin_amdgcn_mfma_f32_16x16x32_bf16(abuf[s % 3][1][kh], wv[kh][ct], acc[1][ct], 0, 0, 0);
        }
    }
#undef LOADA
  } else {
    // Fallback (no workspace): fp32 gather + in-loop conversions.
    const float* xbf = x + (size_t)b * NP * NC + kq * 8;
#pragma unroll
    for (int s = 0; s < NS; ++s) {
      bf16x8 a[2][2];
#pragma unroll
      for (int rt = 0; rt < 2; ++rt) {
        const float* src = xbf + (size_t)idx[rt][s] * NC;
        float4 f0 = *(const float4*)src, f1 = *(const float4*)(src + 4);
        float4 g0 = *(const float4*)(src + 32), g1 = *(const float4*)(src + 36);
        u16x8 t0, t1;
        t0[0] = f2bf(f0.x); t0[1] = f2bf(f0.y); t0[2] = f2bf(f0.z); t0[3] = f2bf(f0.w);
        t0[4] = f2bf(f1.x); t0[5] = f2bf(f1.y); t0[6] = f2bf(f1.z); t0[7] = f2bf(f1.w);
        t1[0] = f2bf(g0.x); t1[1] = f2bf(g0.y); t1[2] = f2bf(g0.z); t1[3] = f2bf(g0.w);
        t1[4] = f2bf(g1.x); t1[5] = f2bf(g1.y); t1[6] = f2bf(g1.z); t1[7] = f2bf(g1.w);
        a[rt][0] = __builtin_bit_cast(bf16x8, t0);
        a[rt][1] = __builtin_bit_cast(bf16x8, t1);
      }
#pragma unroll
      for (int ct = 0; ct < 4; ++ct) {
#pragma unroll
        for (int kh = 0; kh < 2; ++kh) {
          int col = ct * 16 + lr;
          int kb  = s * 64 + kh * 32 + (kq << 3);
          const float4* wp = (const float4*)&W[col * 576 + kb];
          float4 w0 = wp[0], w1 = wp[1];
          u16x8 t;
          t[0] = f2bf(w0.x); t[1] = f2bf(w0.y); t[2] = f2bf(w0.z); t[3] = f2bf(w0.w);
          t[4] = f2bf(w1.x); t[5] = f2bf(w1.y); t[6] = f2bf(w1.z); t[7] = f2bf(w1.w);
          bf16x8 bf = __builtin_bit_cast(bf16x8, t);
          acc[0][ct] = __builtin_amdgcn_mfma_f32_16x16x32_bf16(a[0][kh], bf, acc[0][ct], 0, 0, 0);
          acc[1][ct] = __builtin_amdgcn_mfma_f32_16x16x32_bf16(a[1][kh], bf, acc[1][ct], 0, 0, 0);
        }
      }
    }
  }

  // epilogue: bias + ELU + pad-vertex mask + store
  // D layout (verified m89): col = lane&15, row = (lane>>4)*4 + reg
  const int orow = w * 16 + (kq << 2);
#pragma unroll
  for (int rt = 0; rt < 2; ++rt) {
#pragma unroll
    for (int ct = 0; ct < 4; ++ct) {
      int col = ct * 16 + lr;
      float bv = bias[col];
#pragma unroll
      for (int r = 0; r < 4; ++r) {
        int n = n0 + rt * 64 + orow + r;
        if (n < NP) {
          float v = acc[rt][ct][r] + bv;
          v = (v > 0.f) ? v : expm1f(v);
          if (n == NP - 1) v = 0.f;
          out[((size_t)b * NP + n) * NO + col] = v;
        }
      }
    }
  }
}

extern "C" void kernel_launch(void* const* d_in, const int* in_sizes, int n_in,
                              void* d_out, int out_size, void* d_ws, size_t ws_size,
                              hipStream_t stream) {
  const float* x    = (const float*)d_in[0];
  // d_in[1] = t_vertex (unused by the reference computation)
  const void*  adj  = d_in[2];
  const float* W    = (const float*)d_in[3];
  const float* bias = (const float*)d_in[4];
  float* out = (float*)d_out;

  const size_t wbytes = (size_t)NS * 2 * 4 * 64 * 8 * 2;        // 73728
  const size_t xbytes = (size_t)NB * NP * NC * 2;               // 30,720,000
  const int nblk = ((NP + 127) / 128) * NB;                     // 235*8 = 1880

  if (ws_size >= wbytes + xbytes) {
    unsigned short* wfrag = (unsigned short*)d_ws;
    unsigned short* xh    = (unsigned short*)((char*)d_ws + wbytes);
    prep_w_kernel<<<18, 256, 0, stream>>>(W, wfrag);
    prep_x_kernel<<<(int)((NB * NP * NC / 8 + 255) / 256), 256, 0, stream>>>(x, xh);
    spiral_main<true><<<nblk, 256, 0, stream>>>(x, adj, W, bias, xh, wfrag, out);
  } else {
    spiral_main<false><<<nblk, 256, 0, stream>>>(x, adj, W, bias, nullptr, nullptr, out);
  }
}

// Round 4
// 84.334 us; speedup vs baseline: 1.1663x; 1.0945x over previous
//
#include <hip/hip_runtime.h>
#include <cstddef>
#include <cmath>

#define NB 8
#define NP 30000
#define NS 9
#define NC 64          // in channels
#define NO 64          // out channels

typedef __bf16 bf16x8 __attribute__((ext_vector_type(8)));
typedef unsigned short u16x8 __attribute__((ext_vector_type(8)));
typedef float f32x4 __attribute__((ext_vector_type(4)));

__device__ __forceinline__ unsigned short f2bf(float f) {
  unsigned int u = __float_as_uint(f);
  u += 0x7FFFu + ((u >> 16) & 1u);   // round-to-nearest-even
  return (unsigned short)(u >> 16);
}

// --- fused prep: blocks [0,18) build W bf16 fragments; rest convert x fp32->bf16 ---
// W frag id = (s*2 + kh)*4 + ct ; within frag: lane*8 + j (16B/lane contiguous)
// value = W[ct*16 + (lane&15)][s*64 + kh*32 + (lane>>4)*8 + j]
__global__ __launch_bounds__(256) void prep_all(const float* __restrict__ x,
                                                const float* __restrict__ W,
                                                unsigned short* __restrict__ xh,
                                                unsigned short* __restrict__ wf) {
  int blk = blockIdx.x;
  if (blk < 18) {
    int t = blk * 256 + threadIdx.x;
    if (t >= NS * 2 * 4 * 64) return;
    int lane = t & 63;
    int ct = (t >> 6) & 3;
    int kh = (t >> 8) & 1;
    int s  = t >> 9;
    int col = ct * 16 + (lane & 15);
    int kb  = s * 64 + kh * 32 + ((lane >> 4) << 3);
    u16x8 v;
#pragma unroll
    for (int j = 0; j < 8; ++j) v[j] = f2bf(W[col * 576 + kb + j]);
    *(u16x8*)&wf[t * 8] = v;
  } else {
    size_t i = ((size_t)(blk - 18) * 256 + threadIdx.x) * 8;
    if (i >= (size_t)NB * NP * NC) return;
    float4 f0 = *(const float4*)(x + i);
    float4 f1 = *(const float4*)(x + i + 4);
    u16x8 v;
    v[0] = f2bf(f0.x); v[1] = f2bf(f0.y); v[2] = f2bf(f0.z); v[3] = f2bf(f0.w);
    v[4] = f2bf(f1.x); v[5] = f2bf(f1.y); v[6] = f2bf(f1.z); v[7] = f2bf(f1.w);
    *(u16x8*)&xh[i] = v;
  }
}

// Barrier-free gather-GEMM with an inline-asm software pipeline:
// all hot-loop VMEM is asm global_load_dwordx4 in pinned issue order,
// counted s_waitcnt vmcnt(N) + sched_barrier(0) before each MFMA cluster.
// A gather: depth-2 prefetch; W stream: depth-1 double buffer.
template<bool FULL>
__global__ __launch_bounds__(256, 3) void spiral_main(
    const float* __restrict__ x, const void* __restrict__ adj_raw,
    const float* __restrict__ W, const float* __restrict__ bias,
    const unsigned short* __restrict__ xh, const unsigned short* __restrict__ wf,
    float* __restrict__ out) {
  const int tid = threadIdx.x;
  const int bid = blockIdx.x;
  const int b    = bid & 7;     // batch -> XCD pinning (bid%8 round-robin)
  const int tile = bid >> 3;
  const int n0 = tile * 128;
  const int w  = tid >> 6;
  const int l  = tid & 63;
  const int lr = l & 15;        // A/D row-within-16, B/D col-within-16
  const int kq = l >> 4;        // k-chunk 0..3

  // spiral_adj may arrive as int32 or int64; int64 (values < 2^31) has all
  // odd 32-bit words == 0. Uniform, data-driven, deterministic detection.
  const int* a32 = (const int*)adj_raw;
  const long long* a64 = (const long long*)adj_raw;
  const bool is64 = ((a32[1] | a32[3] | a32[5] | a32[7]) == 0);

  // Packed gather indices: lo 16 bits = row-tile 0, hi 16 = row-tile 1 (NP < 65536).
  unsigned int pidx[NS];
#pragma unroll
  for (int s = 0; s < NS; ++s) {
    unsigned int pv = 0;
#pragma unroll
    for (int rt = 0; rt < 2; ++rt) {
      int n = n0 + rt * 64 + w * 16 + lr;
      int nc = (n < NP) ? n : 0;
      size_t pos = (((size_t)b * NP + nc) * NS) + s;
      long long vv = is64 ? a64[pos] : (long long)a32[pos];
      int vi = (int)vv;
      if ((unsigned)vi >= (unsigned)NP) vi = 0;
      pv |= ((unsigned int)vi) << (rt * 16);
    }
    pidx[s] = pv;
  }

  // bias preloaded BEFORE the asm region so no compiler VMEM lands inside the
  // counted-vmcnt window; sched_barrier fences it.
  float bv[4];
#pragma unroll
  for (int ct = 0; ct < 4; ++ct) bv[ct] = bias[ct * 16 + lr];

  f32x4 acc[2][4] = {};

  if (FULL) {
    const unsigned short* xb    = xh + (size_t)b * NP * NC + kq * 8;
    const unsigned short* wlane = wf + (size_t)l * 8;

    uint4 abuf[3][2][2];   // [slot][row-tile][k-half]
    uint4 wreg[2][2][4];   // [slot][k-half][col-tile]

    __builtin_amdgcn_sched_barrier(0);

#define ISSUE_A(S)                                                                                  \
    if ((S) < NS) {                                                                                 \
      unsigned int pv = pidx[(S)];                                                                  \
      const unsigned short* s0 = xb + (size_t)(pv & 0xFFFFu) * NC;                                  \
      const unsigned short* s1 = xb + (size_t)(pv >> 16) * NC;                                      \
      asm volatile("global_load_dwordx4 %0, %1, off"           : "=v"(abuf[(S)%3][0][0]) : "v"(s0));\
      asm volatile("global_load_dwordx4 %0, %1, off offset:64" : "=v"(abuf[(S)%3][0][1]) : "v"(s0));\
      asm volatile("global_load_dwordx4 %0, %1, off"           : "=v"(abuf[(S)%3][1][0]) : "v"(s1));\
      asm volatile("global_load_dwordx4 %0, %1, off offset:64" : "=v"(abuf[(S)%3][1][1]) : "v"(s1));\
    }

#define LOADW4(DST, BASE)                                                                           \
    asm volatile("global_load_dwordx4 %0, %1, off"             : "=v"((DST)[0]) : "v"(BASE));       \
    asm volatile("global_load_dwordx4 %0, %1, off offset:1024" : "=v"((DST)[1]) : "v"(BASE));       \
    asm volatile("global_load_dwordx4 %0, %1, off offset:2048" : "=v"((DST)[2]) : "v"(BASE));       \
    asm volatile("global_load_dwordx4 %0, %1, off offset:3072" : "=v"((DST)[3]) : "v"(BASE));

#define ISSUE_W(S)                                                                                  \
    if ((S) < NS) {                                                                                 \
      const unsigned short* wk0 = wlane + (S) * 4096;                                               \
      const unsigned short* wk1 = wk0 + 2048;                                                       \
      LOADW4(wreg[(S)%2][0], wk0);                                                                  \
      LOADW4(wreg[(S)%2][1], wk1);                                                                  \
    }

#define WAITVM(N)                                                                                   \
    asm volatile("s_waitcnt vmcnt(" #N ")" ::: "memory");                                           \
    __builtin_amdgcn_sched_barrier(0);

#define MFMA16(S)                                                                                   \
    _Pragma("unroll")                                                                               \
    for (int ct = 0; ct < 4; ++ct) {                                                                \
      _Pragma("unroll")                                                                             \
      for (int kh = 0; kh < 2; ++kh) {                                                              \
        bf16x8 wv = __builtin_bit_cast(bf16x8, wreg[(S)%2][kh][ct]);                                \
        acc[0][ct] = __builtin_amdgcn_mfma_f32_16x16x32_bf16(                                       \
            __builtin_bit_cast(bf16x8, abuf[(S)%3][0][kh]), wv, acc[0][ct], 0, 0, 0);               \
        acc[1][ct] = __builtin_amdgcn_mfma_f32_16x16x32_bf16(                                       \
            __builtin_bit_cast(bf16x8, abuf[(S)%3][1][kh]), wv, acc[1][ct], 0, 0, 0);               \
      }                                                                                             \
    }

// Steady-state wait arithmetic (issue order: A0 W0 A1 | [W(s+1) A(s+2) wait]...):
// before MFMA(s) the allowed-outstanding set is A(s+1),A(s+2),W(s+1) = 4+4+8 = 16.
// Tail: s=7 -> A8+W8 = 12; s=8 -> 0.
#define STEP(S, VMLIT)                                                                              \
    ISSUE_W((S) + 1);                                                                               \
    ISSUE_A((S) + 2);                                                                               \
    WAITVM(VMLIT);                                                                                  \
    MFMA16(S);

    // prologue (age order A0, W0, A1 — required by the counts above)
    ISSUE_A(0);
    ISSUE_W(0);
    ISSUE_A(1);

    STEP(0, 16);
    STEP(1, 16);
    STEP(2, 16);
    STEP(3, 16);
    STEP(4, 16);
    STEP(5, 16);
    STEP(6, 16);
    STEP(7, 12);
    STEP(8, 0);

#undef STEP
#undef MFMA16
#undef WAITVM
#undef ISSUE_W
#undef LOADW4
#undef ISSUE_A
  } else {
    // Fallback (no workspace): fp32 gather + in-loop conversions, compiler-scheduled.
    const float* xbf = x + (size_t)b * NP * NC + kq * 8;
#pragma unroll
    for (int s = 0; s < NS; ++s) {
      bf16x8 a[2][2];
#pragma unroll
      for (int rt = 0; rt < 2; ++rt) {
        unsigned int pv = pidx[s];
        int iv = (rt == 0) ? (int)(pv & 0xFFFFu) : (int)(pv >> 16);
        const float* src = xbf + (size_t)iv * NC;
        float4 f0 = *(const float4*)src, f1 = *(const float4*)(src + 4);
        float4 g0 = *(const float4*)(src + 32), g1 = *(const float4*)(src + 36);
        u16x8 t0, t1;
        t0[0] = f2bf(f0.x); t0[1] = f2bf(f0.y); t0[2] = f2bf(f0.z); t0[3] = f2bf(f0.w);
        t0[4] = f2bf(f1.x); t0[5] = f2bf(f1.y); t0[6] = f2bf(f1.z); t0[7] = f2bf(f1.w);
        t1[0] = f2bf(g0.x); t1[1] = f2bf(g0.y); t1[2] = f2bf(g0.z); t1[3] = f2bf(g0.w);
        t1[4] = f2bf(g1.x); t1[5] = f2bf(g1.y); t1[6] = f2bf(g1.z); t1[7] = f2bf(g1.w);
        a[rt][0] = __builtin_bit_cast(bf16x8, t0);
        a[rt][1] = __builtin_bit_cast(bf16x8, t1);
      }
#pragma unroll
      for (int ct = 0; ct < 4; ++ct) {
#pragma unroll
        for (int kh = 0; kh < 2; ++kh) {
          int col = ct * 16 + lr;
          int kb  = s * 64 + kh * 32 + (kq << 3);
          const float4* wp = (const float4*)&W[col * 576 + kb];
          float4 w0 = wp[0], w1 = wp[1];
          u16x8 t;
          t[0] = f2bf(w0.x); t[1] = f2bf(w0.y); t[2] = f2bf(w0.z); t[3] = f2bf(w0.w);
          t[4] = f2bf(w1.x); t[5] = f2bf(w1.y); t[6] = f2bf(w1.z); t[7] = f2bf(w1.w);
          bf16x8 bf = __builtin_bit_cast(bf16x8, t);
          acc[0][ct] = __builtin_amdgcn_mfma_f32_16x16x32_bf16(a[0][kh], bf, acc[0][ct], 0, 0, 0);
          acc[1][ct] = __builtin_amdgcn_mfma_f32_16x16x32_bf16(a[1][kh], bf, acc[1][ct], 0, 0, 0);
        }
      }
    }
  }

  // epilogue: bias + ELU + pad-vertex mask + store
  // D layout (verified m89): col = lane&15, row = (lane>>4)*4 + reg
  const int orow = w * 16 + (kq << 2);
#pragma unroll
  for (int rt = 0; rt < 2; ++rt) {
#pragma unroll
    for (int ct = 0; ct < 4; ++ct) {
      int col = ct * 16 + lr;
#pragma unroll
      for (int r = 0; r < 4; ++r) {
        int n = n0 + rt * 64 + orow + r;
        if (n < NP) {
          float v = acc[rt][ct][r] + bv[ct];
          v = (v > 0.f) ? v : expm1f(v);
          if (n == NP - 1) v = 0.f;
          out[((size_t)b * NP + n) * NO + col] = v;
        }
      }
    }
  }
}

extern "C" void kernel_launch(void* const* d_in, const int* in_sizes, int n_in,
                              void* d_out, int out_size, void* d_ws, size_t ws_size,
                              hipStream_t stream) {
  const float* x    = (const float*)d_in[0];
  // d_in[1] = t_vertex (unused by the reference computation)
  const void*  adj  = d_in[2];
  const float* W    = (const float*)d_in[3];
  const float* bias = (const float*)d_in[4];
  float* out = (float*)d_out;

  const size_t wbytes = (size_t)NS * 2 * 4 * 64 * 8 * 2;        // 73728
  const size_t xbytes = (size_t)NB * NP * NC * 2;               // 30,720,000
  const int nblk = ((NP + 127) / 128) * NB;                     // 235*8 = 1880

  if (ws_size >= wbytes + xbytes) {
    unsigned short* wfrag = (unsigned short*)d_ws;
    unsigned short* xh    = (unsigned short*)((char*)d_ws + wbytes);
    const int xblk = (int)((NB * NP * NC / 8 + 255) / 256);     // 7500
    prep_all<<<18 + xblk, 256, 0, stream>>>(x, W, xh, wfrag);
    spiral_main<true><<<nblk, 256, 0, stream>>>(x, adj, W, bias, xh, wfrag, out);
  } else {
    spiral_main<false><<<nblk, 256, 0, stream>>>(x, adj, W, bias, nullptr, nullptr, out);
  }
}

// Round 5
// 75.635 us; speedup vs baseline: 1.3004x; 1.1150x over previous
//
#include <hip/hip_runtime.h>
#include <cstddef>
#include <cmath>

#define NB 8
#define NP 30000
#define NPP 30080        // padded N for adjT (multiple of 128)
#define NS 9
#define NC 64            // in channels
#define NO 64            // out channels

typedef __bf16 bf16x8 __attribute__((ext_vector_type(8)));
typedef unsigned short u16x8 __attribute__((ext_vector_type(8)));
typedef float f32x4 __attribute__((ext_vector_type(4)));

__device__ __forceinline__ unsigned short f2bf(float f) {
  unsigned int u = __float_as_uint(f);
  u += 0x7FFFu + ((u >> 16) & 1u);   // round-to-nearest-even
  return (unsigned short)(u >> 16);
}

__device__ __forceinline__ void gload_lds16(const void* g, void* l) {
  __builtin_amdgcn_global_load_lds(
      (const __attribute__((address_space(1))) unsigned int*)g,
      (__attribute__((address_space(3))) unsigned int*)l, 16, 0, 0);
}

__device__ __forceinline__ unsigned lds_off(void* p) {
  return (unsigned)(unsigned long long)(__attribute__((address_space(3))) char*)p;
}

// --- fused prep, 3 block ranges ---
// [0,18): W fp32 -> bf16 B-fragments. frag id = (s*2+kh)*4+ct; lane-contiguous 16B.
// [18, 18+8496): adj -> adjT int16 [b][s][NPP], clamped, pad rows = 0.
// [18+8496, +7500): x fp32 -> bf16.
__global__ __launch_bounds__(256) void prep_all(const float* __restrict__ x,
                                                const float* __restrict__ W,
                                                const void* __restrict__ adj_raw,
                                                unsigned short* __restrict__ wf,
                                                unsigned short* __restrict__ adjT,
                                                unsigned short* __restrict__ xh) {
  int blk = blockIdx.x;
  if (blk < 18) {
    int t = blk * 256 + threadIdx.x;
    if (t >= NS * 2 * 4 * 64) return;
    int lane = t & 63;
    int ct = (t >> 6) & 3;
    int kh = (t >> 8) & 1;
    int s  = t >> 9;
    int col = ct * 16 + (lane & 15);
    int kb  = s * 64 + kh * 32 + ((lane >> 4) << 3);
    u16x8 v;
#pragma unroll
    for (int j = 0; j < 8; ++j) v[j] = f2bf(W[col * 576 + kb + j]);
    *(u16x8*)&wf[t * 8] = v;
  } else if (blk < 18 + 72 * 118) {
    int blk2 = blk - 18;
    int sb = blk2 / 118, nb = blk2 - sb * 118;
    int n = nb * 256 + threadIdx.x;
    if (n >= NPP) return;
    unsigned short v = 0;
    if (n < NP) {
      int b = sb / 9, s = sb - b * 9;
      const int* a32 = (const int*)adj_raw;
      const long long* a64 = (const long long*)adj_raw;
      // int64 adj (values < 2^31) has all odd 32-bit words == 0.
      bool is64 = ((a32[1] | a32[3] | a32[5] | a32[7]) == 0);
      size_t pos = ((size_t)b * NP + n) * NS + s;
      long long vv = is64 ? a64[pos] : (long long)a32[pos];
      int vi = (int)vv;
      if ((unsigned)vi >= (unsigned)NP) vi = 0;
      v = (unsigned short)vi;
    }
    adjT[(size_t)sb * NPP + n] = v;
  } else {
    size_t i = ((size_t)(blk - 18 - 8496) * 256 + threadIdx.x) * 8;
    if (i >= (size_t)NB * NP * NC) return;
    float4 f0 = *(const float4*)(x + i);
    float4 f1 = *(const float4*)(x + i + 4);
    u16x8 v;
    v[0] = f2bf(f0.x); v[1] = f2bf(f0.y); v[2] = f2bf(f0.z); v[3] = f2bf(f0.w);
    v[4] = f2bf(f1.x); v[5] = f2bf(f1.y); v[6] = f2bf(f1.z); v[7] = f2bf(f1.w);
    *(u16x8*)&xh[i] = v;
  }
}

// Main: block = 128 rows x 64 cols, 4 waves; wave w owns cols w*16..w*16+15.
// W resident in 72 VGPRs/wave (loaded once). A gathered via global_load_lds
// directly into MFMA-fragment layout in LDS (triple-buffered, stage s+2 during
// step s, counted vmcnt, one barrier per step). Zero bank conflicts by design.
__global__ __launch_bounds__(256, 3) void spiral_pipe(
    const unsigned short* __restrict__ adjT, const float* __restrict__ bias,
    const unsigned short* __restrict__ xh, const unsigned short* __restrict__ wf,
    float* __restrict__ out) {
  __shared__ __align__(16) char Alds[3][16384];   // [buf][frag(rt,kh)=rt*2+kh][lane*16]

  const int tid = threadIdx.x;
  const int bid = blockIdx.x;
  const int b    = bid & 7;      // batch -> XCD pinning
  const int tile = bid >> 3;
  const int n0 = tile * 128;
  const int w  = tid >> 6;
  const int l  = tid & 63;
  const int lr = l & 15;
  const int kq = l >> 4;

  // ---- plain-load region (everything consumed before the fence) ----
  // gather indices: lane lr needs rows n0+32w+lr (rt=2w) and +16 (rt=2w+1), all 9 s.
  unsigned pidx[NS];
#pragma unroll
  for (int s = 0; s < NS; ++s) {
    const unsigned short* ap = adjT + (size_t)(b * NS + s) * NPP + n0 + 32 * w + lr;
    unsigned lo = ap[0], hi = ap[16];
    pidx[s] = lo | (hi << 16);
    asm volatile("" :: "v"(pidx[s]));     // force materialization before fence
  }
  float bvv = bias[w * 16 + lr];
  asm volatile("" :: "v"(bvv));

  const char* xb = (const char*)xh + (size_t)b * NP * 128 + kq * 16;

  asm volatile("s_waitcnt vmcnt(0)" ::: "memory");
  __builtin_amdgcn_sched_barrier(0);

  // ---- counted-VMEM region: only asm loads + global_load_lds below ----
  uint4 wreg[NS][2];
#pragma unroll
  for (int s = 0; s < NS; ++s)
#pragma unroll
    for (int kh = 0; kh < 2; ++kh) {
      const char* wp = (const char*)wf + ((size_t)((s * 2 + kh) * 4 + w) * 64 + l) * 16;
      asm volatile("global_load_dwordx4 %0, %1, off" : "=v"(wreg[s][kh]) : "v"(wp));
    }

#define STAGE(S) {                                                        \
    unsigned pv = pidx[(S)];                                              \
    char* lb = &Alds[(S) % 3][0];                                         \
    unsigned r0 = pv & 0xFFFFu, r1 = pv >> 16;                            \
    const char* g0 = xb + (size_t)r0 * 128;                               \
    const char* g1 = xb + (size_t)r1 * 128;                               \
    gload_lds16(g0,      lb + (4 * w + 0) * 1024);                        \
    gload_lds16(g0 + 64, lb + (4 * w + 1) * 1024);                        \
    gload_lds16(g1,      lb + (4 * w + 2) * 1024);                        \
    gload_lds16(g1 + 64, lb + (4 * w + 3) * 1024);                        \
  }

#define WAITVM(N)                                                         \
    asm volatile("s_waitcnt vmcnt(" #N ")" ::: "memory");                 \
    __builtin_amdgcn_sched_barrier(0);

#define WAITLG                                                            \
    asm volatile("s_waitcnt lgkmcnt(0)" ::: "memory");                    \
    __builtin_amdgcn_sched_barrier(0);

#define RD(DST, OFF)                                                      \
    asm volatile("ds_read_b128 %0, %1 offset:" #OFF : "=v"(DST) : "v"(ab));

#define MF(A, WV, C) __builtin_amdgcn_mfma_f32_16x16x32_bf16(             \
    __builtin_bit_cast(bf16x8, (A)), __builtin_bit_cast(bf16x8, (WV)), (C), 0, 0, 0)

  f32x4 acc[8] = {};
  uint4 a0, a1, a2, a3, a4, a5, a6, a7;

  unsigned abase[3];
#pragma unroll
  for (int bu = 0; bu < 3; ++bu) abase[bu] = lds_off(&Alds[bu][0]) + l * 16;

// G0: frags (rt0-3, kh0/1) at offsets 0..7168; G1: rt4-7 at 8192..15360.
#define GHALF0(S) {                                                       \
    unsigned ab = abase[(S) % 3];                                         \
    RD(a0, 0)    RD(a1, 1024) RD(a2, 2048) RD(a3, 3072)                   \
    RD(a4, 4096) RD(a5, 5120) RD(a6, 6144) RD(a7, 7168)                   \
    WAITLG                                                                \
    acc[0] = MF(a0, wreg[(S)][0], acc[0]);                                \
    acc[0] = MF(a1, wreg[(S)][1], acc[0]);                                \
    acc[1] = MF(a2, wreg[(S)][0], acc[1]);                                \
    acc[1] = MF(a3, wreg[(S)][1], acc[1]);                                \
    acc[2] = MF(a4, wreg[(S)][0], acc[2]);                                \
    acc[2] = MF(a5, wreg[(S)][1], acc[2]);                                \
    acc[3] = MF(a6, wreg[(S)][0], acc[3]);                                \
    acc[3] = MF(a7, wreg[(S)][1], acc[3]);                                \
  }
#define GHALF1(S) {                                                       \
    unsigned ab = abase[(S) % 3];                                         \
    RD(a0, 8192)  RD(a1, 9216)  RD(a2, 10240) RD(a3, 11264)               \
    RD(a4, 12288) RD(a5, 13312) RD(a6, 14336) RD(a7, 15360)               \
    WAITLG                                                                \
    acc[4] = MF(a0, wreg[(S)][0], acc[4]);                                \
    acc[4] = MF(a1, wreg[(S)][1], acc[4]);                                \
    acc[5] = MF(a2, wreg[(S)][0], acc[5]);                                \
    acc[5] = MF(a3, wreg[(S)][1], acc[5]);                                \
    acc[6] = MF(a4, wreg[(S)][0], acc[6]);                                \
    acc[6] = MF(a5, wreg[(S)][1], acc[6]);                                \
    acc[7] = MF(a6, wreg[(S)][0], acc[7]);                                \
    acc[7] = MF(a7, wreg[(S)][1], acc[7]);                                \
  }

  // prologue: stage bufs 0,1. Outstanding: W(18)+stage0(4)+stage1(4).
  STAGE(0)
  STAGE(1)
  WAITVM(4)                       // W + stage0 complete; stage1 in flight
  __builtin_amdgcn_s_barrier();

#define STEP_MID(S)                                                       \
    STAGE((S) + 2)                                                        \
    GHALF0(S) GHALF1(S)                                                   \
    WAITVM(4)                                                             \
    __builtin_amdgcn_s_barrier();

  STEP_MID(0)
  STEP_MID(1)
  STEP_MID(2)
  STEP_MID(3)
  STEP_MID(4)
  STEP_MID(5)
  STEP_MID(6)
  // step 7: no stage(9); drain so stage(8) is complete
  GHALF0(7) GHALF1(7)
  WAITVM(0)
  __builtin_amdgcn_s_barrier();
  // step 8: last, no tail sync
  GHALF0(8) GHALF1(8)

#undef STEP_MID
#undef GHALF1
#undef GHALF0
#undef MF
#undef RD
#undef WAITLG
#undef WAITVM
#undef STAGE

  // epilogue: bias + ELU + mask + store. D: col=lane&15, row=(lane>>4)*4+reg.
  const int col = w * 16 + lr;
#pragma unroll
  for (int rt = 0; rt < 8; ++rt) {
#pragma unroll
    for (int r = 0; r < 4; ++r) {
      int n = n0 + rt * 16 + kq * 4 + r;
      if (n < NP) {
        float v = acc[rt][r] + bvv;
        v = (v > 0.f) ? v : expm1f(v);
        if (n == NP - 1) v = 0.f;
        out[((size_t)b * NP + n) * NO + col] = v;
      }
    }
  }
}

// Fallback (workspace too small): R4's fp32 direct path, compiler-scheduled.
__global__ __launch_bounds__(256, 3) void spiral_fb(
    const float* __restrict__ x, const void* __restrict__ adj_raw,
    const float* __restrict__ W, const float* __restrict__ bias,
    float* __restrict__ out) {
  const int tid = threadIdx.x;
  const int bid = blockIdx.x;
  const int b    = bid & 7;
  const int tile = bid >> 3;
  const int n0 = tile * 128;
  const int w  = tid >> 6;
  const int l  = tid & 63;
  const int lr = l & 15;
  const int kq = l >> 4;

  const int* a32 = (const int*)adj_raw;
  const long long* a64 = (const long long*)adj_raw;
  const bool is64 = ((a32[1] | a32[3] | a32[5] | a32[7]) == 0);

  int idx[2][NS];
#pragma unroll
  for (int rt = 0; rt < 2; ++rt) {
    int n = n0 + rt * 64 + w * 16 + lr;
    int nc = (n < NP) ? n : 0;
    size_t base = ((size_t)b * NP + nc) * NS;
#pragma unroll
    for (int s = 0; s < NS; ++s) {
      long long vv = is64 ? a64[base + s] : (long long)a32[base + s];
      int vi = (int)vv;
      idx[rt][s] = ((unsigned)vi < (unsigned)NP) ? vi : 0;
    }
  }

  f32x4 acc[2][4] = {};
  const float* xbf = x + (size_t)b * NP * NC + kq * 8;
#pragma unroll
  for (int s = 0; s < NS; ++s) {
    bf16x8 a[2][2];
#pragma unroll
    for (int rt = 0; rt < 2; ++rt) {
      const float* src = xbf + (size_t)idx[rt][s] * NC;
      float4 f0 = *(const float4*)src, f1 = *(const float4*)(src + 4);
      float4 g0 = *(const float4*)(src + 32), g1 = *(const float4*)(src + 36);
      u16x8 t0, t1;
      t0[0] = f2bf(f0.x); t0[1] = f2bf(f0.y); t0[2] = f2bf(f0.z); t0[3] = f2bf(f0.w);
      t0[4] = f2bf(f1.x); t0[5] = f2bf(f1.y); t0[6] = f2bf(f1.z); t0[7] = f2bf(f1.w);
      t1[0] = f2bf(g0.x); t1[1] = f2bf(g0.y); t1[2] = f2bf(g0.z); t1[3] = f2bf(g0.w);
      t1[4] = f2bf(g1.x); t1[5] = f2bf(g1.y); t1[6] = f2bf(g1.z); t1[7] = f2bf(g1.w);
      a[rt][0] = __builtin_bit_cast(bf16x8, t0);
      a[rt][1] = __builtin_bit_cast(bf16x8, t1);
    }
#pragma unroll
    for (int ct = 0; ct < 4; ++ct) {
#pragma unroll
      for (int kh = 0; kh < 2; ++kh) {
        int col = ct * 16 + lr;
        int kb  = s * 64 + kh * 32 + (kq << 3);
        const float4* wp = (const float4*)&W[col * 576 + kb];
        float4 w0 = wp[0], w1 = wp[1];
        u16x8 t;
        t[0] = f2bf(w0.x); t[1] = f2bf(w0.y); t[2] = f2bf(w0.z); t[3] = f2bf(w0.w);
        t[4] = f2bf(w1.x); t[5] = f2bf(w1.y); t[6] = f2bf(w1.z); t[7] = f2bf(w1.w);
        bf16x8 bf = __builtin_bit_cast(bf16x8, t);
        acc[0][ct] = __builtin_amdgcn_mfma_f32_16x16x32_bf16(a[0][kh], bf, acc[0][ct], 0, 0, 0);
        acc[1][ct] = __builtin_amdgcn_mfma_f32_16x16x32_bf16(a[1][kh], bf, acc[1][ct], 0, 0, 0);
      }
    }
  }

  const int orow = w * 16 + (kq << 2);
#pragma unroll
  for (int rt = 0; rt < 2; ++rt) {
#pragma unroll
    for (int ct = 0; ct < 4; ++ct) {
      int col = ct * 16 + lr;
      float bv = bias[col];
#pragma unroll
      for (int r = 0; r < 4; ++r) {
        int n = n0 + rt * 64 + orow + r;
        if (n < NP) {
          float v = acc[rt][ct][r] + bv;
          v = (v > 0.f) ? v : expm1f(v);
          if (n == NP - 1) v = 0.f;
          out[((size_t)b * NP + n) * NO + col] = v;
        }
      }
    }
  }
}

extern "C" void kernel_launch(void* const* d_in, const int* in_sizes, int n_in,
                              void* d_out, int out_size, void* d_ws, size_t ws_size,
                              hipStream_t stream) {
  const float* x    = (const float*)d_in[0];
  // d_in[1] = t_vertex (unused by the reference computation)
  const void*  adj  = d_in[2];
  const float* W    = (const float*)d_in[3];
  const float* bias = (const float*)d_in[4];
  float* out = (float*)d_out;

  const size_t wbytes = (size_t)NS * 2 * 4 * 64 * 8 * 2;            // 73728
  const size_t abytes = (size_t)NB * NS * NPP * 2;                  // 4,331,520
  const size_t xbytes = (size_t)NB * NP * NC * 2;                   // 30,720,000
  const int nblk = ((NP + 127) / 128) * NB;                         // 1880

  if (ws_size >= wbytes + abytes + xbytes) {
    unsigned short* wfrag = (unsigned short*)d_ws;
    unsigned short* adjT  = (unsigned short*)((char*)d_ws + wbytes);
    unsigned short* xh    = (unsigned short*)((char*)d_ws + wbytes + abytes);
    prep_all<<<18 + 8496 + 7500, 256, 0, stream>>>(x, W, adj, wfrag, adjT, xh);
    spiral_pipe<<<nblk, 256, 0, stream>>>(adjT, bias, xh, wfrag, out);
  } else {
    spiral_fb<<<nblk, 256, 0, stream>>>(x, adj, W, bias, out);
  }
}

// Round 6
// 70.314 us; speedup vs baseline: 1.3988x; 1.0757x over previous
//
#include <hip/hip_runtime.h>
#include <cstddef>
#include <cmath>

#define NB 8
#define NP 30000
#define NPP 30080        // padded N for adjT (multiple of 128)
#define NS 9
#define NC 64            // in channels
#define NO 64            // out channels
#define NT 235           // row tiles of 128
#define GBLK 512         // main grid: 64 tile-strides x 8 batches

typedef __bf16 bf16x8 __attribute__((ext_vector_type(8)));
typedef unsigned short u16x8 __attribute__((ext_vector_type(8)));
typedef float f32x4 __attribute__((ext_vector_type(4)));

__device__ __forceinline__ unsigned short f2bf(float f) {
  unsigned int u = __float_as_uint(f);
  u += 0x7FFFu + ((u >> 16) & 1u);   // round-to-nearest-even
  return (unsigned short)(u >> 16);
}

__device__ __forceinline__ void gload_lds16(const void* g, void* l) {
  __builtin_amdgcn_global_load_lds(
      (const __attribute__((address_space(1))) unsigned int*)g,
      (__attribute__((address_space(3))) unsigned int*)l, 16, 0, 0);
}

__device__ __forceinline__ unsigned lds_off(void* p) {
  return (unsigned)(unsigned long long)(__attribute__((address_space(3))) char*)p;
}

// --- fused prep, 3 block ranges ---
// [0,18): W fp32 -> bf16 B-fragments. frag id = (s*2+kh)*4+ct; lane-contiguous 16B.
// [18, 18+8496): adj -> adjT int16 [b][s][NPP], clamped, pad rows = 0.
// [18+8496, +7500): x fp32 -> bf16.
__global__ __launch_bounds__(256) void prep_all(const float* __restrict__ x,
                                                const float* __restrict__ W,
                                                const void* __restrict__ adj_raw,
                                                unsigned short* __restrict__ wf,
                                                unsigned short* __restrict__ adjT,
                                                unsigned short* __restrict__ xh) {
  int blk = blockIdx.x;
  if (blk < 18) {
    int t = blk * 256 + threadIdx.x;
    if (t >= NS * 2 * 4 * 64) return;
    int lane = t & 63;
    int ct = (t >> 6) & 3;
    int kh = (t >> 8) & 1;
    int s  = t >> 9;
    int col = ct * 16 + (lane & 15);
    int kb  = s * 64 + kh * 32 + ((lane >> 4) << 3);
    u16x8 v;
#pragma unroll
    for (int j = 0; j < 8; ++j) v[j] = f2bf(W[col * 576 + kb + j]);
    *(u16x8*)&wf[t * 8] = v;
  } else if (blk < 18 + 72 * 118) {
    int blk2 = blk - 18;
    int sb = blk2 / 118, nb = blk2 - sb * 118;
    int n = nb * 256 + threadIdx.x;
    if (n >= NPP) return;
    unsigned short v = 0;
    if (n < NP) {
      int b = sb / 9, s = sb - b * 9;
      const int* a32 = (const int*)adj_raw;
      const long long* a64 = (const long long*)adj_raw;
      // int64 adj (values < 2^31) has all odd 32-bit words == 0.
      bool is64 = ((a32[1] | a32[3] | a32[5] | a32[7]) == 0);
      size_t pos = ((size_t)b * NP + n) * NS + s;
      long long vv = is64 ? a64[pos] : (long long)a32[pos];
      int vi = (int)vv;
      if ((unsigned)vi >= (unsigned)NP) vi = 0;
      v = (unsigned short)vi;
    }
    adjT[(size_t)sb * NPP + n] = v;
  } else {
    size_t i = ((size_t)(blk - 18 - 8496) * 256 + threadIdx.x) * 8;
    if (i >= (size_t)NB * NP * NC) return;
    float4 f0 = *(const float4*)(x + i);
    float4 f1 = *(const float4*)(x + i + 4);
    u16x8 v;
    v[0] = f2bf(f0.x); v[1] = f2bf(f0.y); v[2] = f2bf(f0.z); v[3] = f2bf(f0.w);
    v[4] = f2bf(f1.x); v[5] = f2bf(f1.y); v[6] = f2bf(f1.z); v[7] = f2bf(f1.w);
    *(u16x8*)&xh[i] = v;
  }
}

// Main: grid-stride over 128-row tiles; block = 128 rows x 64 cols, 4 waves.
// Wave (wr,wc) = rows wr*64..+63, cols wc*32..+31 -> LDS read amp 2x (was 4x).
// W resident in 144 VGPR/wave, loaded ONCE per block (grid-stride amortizes).
// A staged via global_load_lds into fragment layout (triple buffer, depth-2,
// counted vmcnt); ds_read->MFMA paced by counted lgkmcnt (no drains).
__global__ __launch_bounds__(256, 2) void spiral_pipe(
    const unsigned short* __restrict__ adjT, const float* __restrict__ bias,
    const unsigned short* __restrict__ xh, const unsigned short* __restrict__ wf,
    float* __restrict__ out) {
  __shared__ __align__(16) char Alds[3][16384];   // [buf][frag = rt*2+kh][lane*16]

  const int tid = threadIdx.x;
  const int bid = blockIdx.x;
  const int b  = bid & 7;        // batch -> XCD pinning
  const int t0 = bid >> 3;       // first tile; stride 64
  const int w  = tid >> 6;
  const int l  = tid & 63;
  const int lr = l & 15;
  const int kq = l >> 4;
  const int wr = w >> 1;         // row-half 0/1 (64 rows)
  const int wc = w & 1;          // col-half 0/1 (32 cols)
  const unsigned wrofs = (unsigned)wr * 8192;

  const char* xb = (const char*)xh + (size_t)b * NP * 128 + kq * 16;
  float* outb = out + (size_t)b * NP * NO;
  const float bv0 = bias[wc * 32 + lr];
  const float bv1 = bias[wc * 32 + 16 + lr];

  unsigned abase[3];
#pragma unroll
  for (int bu = 0; bu < 3; ++bu) abase[bu] = lds_off(&Alds[bu][0]) + l * 16;

  // ---- W preload: once per block, asm (part of the hand-counted VMEM set) ----
  uint4 wreg[18][2];
#pragma unroll
  for (int sk = 0; sk < 18; ++sk)
#pragma unroll
    for (int j = 0; j < 2; ++j) {
      const char* wp = (const char*)wf + ((size_t)(sk * 4 + 2 * wc + j) * 64 + l) * 16;
      asm volatile("global_load_dwordx4 %0, %1, off" : "=v"(wreg[sk][j]) : "v"(wp));
    }

#define STAGE(S) {                                                        \
    unsigned pv = pidx[(S)];                                              \
    char* lb = &Alds[(S) % 3][0];                                         \
    unsigned r0 = pv & 0xFFFFu, r1 = pv >> 16;                            \
    const char* g0 = xb + (size_t)r0 * 128;                               \
    const char* g1 = xb + (size_t)r1 * 128;                               \
    gload_lds16(g0,      lb + (4 * w + 0) * 1024);                        \
    gload_lds16(g0 + 64, lb + (4 * w + 1) * 1024);                        \
    gload_lds16(g1,      lb + (4 * w + 2) * 1024);                        \
    gload_lds16(g1 + 64, lb + (4 * w + 3) * 1024);                        \
  }

#define WAITVM(N)                                                         \
    asm volatile("s_waitcnt vmcnt(" #N ")" ::: "memory");                 \
    __builtin_amdgcn_sched_barrier(0);

#define WAITLGN(N)                                                        \
    asm volatile("s_waitcnt lgkmcnt(" #N ")" ::: "memory");               \
    __builtin_amdgcn_sched_barrier(0);

#define RD(DST, OFF)                                                      \
    asm volatile("ds_read_b128 %0, %1 offset:" #OFF : "=v"(DST) : "v"(ab));

#define MF(A, WV, C) __builtin_amdgcn_mfma_f32_16x16x32_bf16(             \
    __builtin_bit_cast(bf16x8, (A)), __builtin_bit_cast(bf16x8, (WV)), (C), 0, 0, 0)

// 8 ds_reads (kh0 frags then kh1 frags of this wave's 4 row-tiles), then
// counted-lgkm paced MFMA pairs; acc dep distance = 8 MFMAs.
#define BODY(S) {                                                         \
    unsigned ab = abase[(S) % 3] + wrofs;                                 \
    uint4 f0, f1, f2, f3, f4, f5, f6, f7;                                 \
    RD(f0, 0)    RD(f1, 2048) RD(f2, 4096) RD(f3, 6144)                   \
    RD(f4, 1024) RD(f5, 3072) RD(f6, 5120) RD(f7, 7168)                   \
    WAITLGN(7) acc[0][0]=MF(f0,wreg[(S)*2][0],acc[0][0]); acc[0][1]=MF(f0,wreg[(S)*2][1],acc[0][1]); \
    WAITLGN(6) acc[1][0]=MF(f1,wreg[(S)*2][0],acc[1][0]); acc[1][1]=MF(f1,wreg[(S)*2][1],acc[1][1]); \
    WAITLGN(5) acc[2][0]=MF(f2,wreg[(S)*2][0],acc[2][0]); acc[2][1]=MF(f2,wreg[(S)*2][1],acc[2][1]); \
    WAITLGN(4) acc[3][0]=MF(f3,wreg[(S)*2][0],acc[3][0]); acc[3][1]=MF(f3,wreg[(S)*2][1],acc[3][1]); \
    WAITLGN(3) acc[0][0]=MF(f4,wreg[(S)*2+1][0],acc[0][0]); acc[0][1]=MF(f4,wreg[(S)*2+1][1],acc[0][1]); \
    WAITLGN(2) acc[1][0]=MF(f5,wreg[(S)*2+1][0],acc[1][0]); acc[1][1]=MF(f5,wreg[(S)*2+1][1],acc[1][1]); \
    WAITLGN(1) acc[2][0]=MF(f6,wreg[(S)*2+1][0],acc[2][0]); acc[2][1]=MF(f6,wreg[(S)*2+1][1],acc[2][1]); \
    WAITLGN(0) acc[3][0]=MF(f7,wreg[(S)*2+1][0],acc[3][0]); acc[3][1]=MF(f7,wreg[(S)*2+1][1],acc[3][1]); \
  }

#define STEP_MID(S)                                                       \
    STAGE((S) + 2)                                                        \
    BODY(S)                                                               \
    WAITVM(4)                                                             \
    __builtin_amdgcn_s_barrier();

  for (int t = t0; t < NT; t += 64) {
    const int n0 = t * 128;

    // per-tile gather indices (plain loads; drained before the counted region)
    unsigned pidx[NS];
#pragma unroll
    for (int s = 0; s < NS; ++s) {
      const unsigned short* ap = adjT + (size_t)(b * NS + s) * NPP + n0 + 32 * w + lr;
      unsigned lo = ap[0], hi = ap[16];
      pidx[s] = lo | (hi << 16);
    }

    f32x4 acc[4][2] = {};

    // drain: W preload (first tile), prior-tile stores, pidx loads -> vmcnt exact
    asm volatile("s_waitcnt vmcnt(0)" ::: "memory");
    __builtin_amdgcn_sched_barrier(0);

    STAGE(0)
    STAGE(1)
    WAITVM(4)                      // stage0 done; stage1 in flight
    __builtin_amdgcn_s_barrier();

    STEP_MID(0)
    STEP_MID(1)
    STEP_MID(2)
    STEP_MID(3)
    STEP_MID(4)
    STEP_MID(5)
    STEP_MID(6)
    BODY(7)
    WAITVM(0)
    __builtin_amdgcn_s_barrier();
    BODY(8)
    __builtin_amdgcn_s_barrier();  // protect buf2 from next tile's STAGE(2)

    // epilogue: bias + cheap ELU (exp-1; |err|~1e-7 << 6e-2 threshold) + mask
    // D layout: col = lane&15, row = (lane>>4)*4 + reg
#pragma unroll
    for (int rt = 0; rt < 4; ++rt) {
#pragma unroll
      for (int j = 0; j < 2; ++j) {
        const int col = wc * 32 + j * 16 + lr;
        const float bv = j ? bv1 : bv0;
#pragma unroll
        for (int r = 0; r < 4; ++r) {
          int n = n0 + wr * 64 + rt * 16 + kq * 4 + r;
          if (n < NP) {
            float v = acc[rt][j][r] + bv;
            v = (v > 0.f) ? v : (__expf(v) - 1.f);
            if (n == NP - 1) v = 0.f;
            outb[(size_t)n * NO + col] = v;
          }
        }
      }
    }
  }

#undef STEP_MID
#undef BODY
#undef MF
#undef RD
#undef WAITLGN
#undef WAITVM
#undef STAGE
}

// Fallback (workspace too small): fp32 direct path, compiler-scheduled.
__global__ __launch_bounds__(256, 3) void spiral_fb(
    const float* __restrict__ x, const void* __restrict__ adj_raw,
    const float* __restrict__ W, const float* __restrict__ bias,
    float* __restrict__ out) {
  const int tid = threadIdx.x;
  const int bid = blockIdx.x;
  const int b    = bid & 7;
  const int tile = bid >> 3;
  const int n0 = tile * 128;
  const int w  = tid >> 6;
  const int l  = tid & 63;
  const int lr = l & 15;
  const int kq = l >> 4;

  const int* a32 = (const int*)adj_raw;
  const long long* a64 = (const long long*)adj_raw;
  const bool is64 = ((a32[1] | a32[3] | a32[5] | a32[7]) == 0);

  int idx[2][NS];
#pragma unroll
  for (int rt = 0; rt < 2; ++rt) {
    int n = n0 + rt * 64 + w * 16 + lr;
    int nc = (n < NP) ? n : 0;
    size_t base = ((size_t)b * NP + nc) * NS;
#pragma unroll
    for (int s = 0; s < NS; ++s) {
      long long vv = is64 ? a64[base + s] : (long long)a32[base + s];
      int vi = (int)vv;
      idx[rt][s] = ((unsigned)vi < (unsigned)NP) ? vi : 0;
    }
  }

  f32x4 acc[2][4] = {};
  const float* xbf = x + (size_t)b * NP * NC + kq * 8;
#pragma unroll
  for (int s = 0; s < NS; ++s) {
    bf16x8 a[2][2];
#pragma unroll
    for (int rt = 0; rt < 2; ++rt) {
      const float* src = xbf + (size_t)idx[rt][s] * NC;
      float4 f0 = *(const float4*)src, f1 = *(const float4*)(src + 4);
      float4 g0 = *(const float4*)(src + 32), g1 = *(const float4*)(src + 36);
      u16x8 t0, t1;
      t0[0] = f2bf(f0.x); t0[1] = f2bf(f0.y); t0[2] = f2bf(f0.z); t0[3] = f2bf(f0.w);
      t0[4] = f2bf(f1.x); t0[5] = f2bf(f1.y); t0[6] = f2bf(f1.z); t0[7] = f2bf(f1.w);
      t1[0] = f2bf(g0.x); t1[1] = f2bf(g0.y); t1[2] = f2bf(g0.z); t1[3] = f2bf(g0.w);
      t1[4] = f2bf(g1.x); t1[5] = f2bf(g1.y); t1[6] = f2bf(g1.z); t1[7] = f2bf(g1.w);
      a[rt][0] = __builtin_bit_cast(bf16x8, t0);
      a[rt][1] = __builtin_bit_cast(bf16x8, t1);
    }
#pragma unroll
    for (int ct = 0; ct < 4; ++ct) {
#pragma unroll
      for (int kh = 0; kh < 2; ++kh) {
        int col = ct * 16 + lr;
        int kb  = s * 64 + kh * 32 + (kq << 3);
        const float4* wp = (const float4*)&W[col * 576 + kb];
        float4 w0 = wp[0], w1 = wp[1];
        u16x8 t;
        t[0] = f2bf(w0.x); t[1] = f2bf(w0.y); t[2] = f2bf(w0.z); t[3] = f2bf(w0.w);
        t[4] = f2bf(w1.x); t[5] = f2bf(w1.y); t[6] = f2bf(w1.z); t[7] = f2bf(w1.w);
        bf16x8 bf = __builtin_bit_cast(bf16x8, t);
        acc[0][ct] = __builtin_amdgcn_mfma_f32_16x16x32_bf16(a[0][kh], bf, acc[0][ct], 0, 0, 0);
        acc[1][ct] = __builtin_amdgcn_mfma_f32_16x16x32_bf16(a[1][kh], bf, acc[1][ct], 0, 0, 0);
      }
    }
  }

  const int orow = w * 16 + (kq << 2);
#pragma unroll
  for (int rt = 0; rt < 2; ++rt) {
#pragma unroll
    for (int ct = 0; ct < 4; ++ct) {
      int col = ct * 16 + lr;
      float bv = bias[col];
#pragma unroll
      for (int r = 0; r < 4; ++r) {
        int n = n0 + rt * 64 + orow + r;
        if (n < NP) {
          float v = acc[rt][ct][r] + bv;
          v = (v > 0.f) ? v : expm1f(v);
          if (n == NP - 1) v = 0.f;
          out[((size_t)b * NP + n) * NO + col] = v;
        }
      }
    }
  }
}

extern "C" void kernel_launch(void* const* d_in, const int* in_sizes, int n_in,
                              void* d_out, int out_size, void* d_ws, size_t ws_size,
                              hipStream_t stream) {
  const float* x    = (const float*)d_in[0];
  // d_in[1] = t_vertex (unused by the reference computation)
  const void*  adj  = d_in[2];
  const float* W    = (const float*)d_in[3];
  const float* bias = (const float*)d_in[4];
  float* out = (float*)d_out;

  const size_t wbytes = (size_t)NS * 2 * 4 * 64 * 8 * 2;            // 73728
  const size_t abytes = (size_t)NB * NS * NPP * 2;                  // 4,331,520
  const size_t xbytes = (size_t)NB * NP * NC * 2;                   // 30,720,000

  if (ws_size >= wbytes + abytes + xbytes) {
    unsigned short* wfrag = (unsigned short*)d_ws;
    unsigned short* adjT  = (unsigned short*)((char*)d_ws + wbytes);
    unsigned short* xh    = (unsigned short*)((char*)d_ws + wbytes + abytes);
    prep_all<<<18 + 8496 + 7500, 256, 0, stream>>>(x, W, adj, wfrag, adjT, xh);
    spiral_pipe<<<GBLK, 256, 0, stream>>>(adjT, bias, xh, wfrag, out);
  } else {
    const int nblk = ((NP + 127) / 128) * NB;
    spiral_fb<<<nblk, 256, 0, stream>>>(x, adj, W, bias, out);
  }
}

// Round 8
// 69.158 us; speedup vs baseline: 1.4222x; 1.0167x over previous
//
#include <hip/hip_runtime.h>
#include <cstddef>
#include <cmath>

#define NB 8
#define NP 30000
#define NPP 30080        // padded N for adjT (multiple of 128)
#define NS 9
#define NC 64            // in channels
#define NO 64            // out channels
#define NT 235           // row tiles of 128
#define GBLK 512         // main grid: 64 tile-strides x 8 batches (2 blocks/CU)

typedef __bf16 bf16x8 __attribute__((ext_vector_type(8)));
typedef unsigned short u16x8 __attribute__((ext_vector_type(8)));
typedef float f32x4 __attribute__((ext_vector_type(4)));

__device__ __forceinline__ unsigned short f2bf(float f) {
  unsigned int u = __float_as_uint(f);
  u += 0x7FFFu + ((u >> 16) & 1u);   // round-to-nearest-even
  return (unsigned short)(u >> 16);
}

__device__ __forceinline__ void gload_lds16(const void* g, void* l) {
  __builtin_amdgcn_global_load_lds(
      (const __attribute__((address_space(1))) unsigned int*)g,
      (__attribute__((address_space(3))) unsigned int*)l, 16, 0, 0);
}

__device__ __forceinline__ unsigned lds_off(void* p) {
  return (unsigned)(unsigned long long)(__attribute__((address_space(3))) char*)p;
}

// --- fused prep, 3 block ranges ---
// [0,18): W fp32 -> bf16 B-fragments. frag id = (s*2+kh)*4+ct; lane-contiguous 16B.
// [18, 18+944): adj -> adjT int16 [b][s][NPP]. One coalesced read of adj[b][n][:]
//               per thread (72B contiguous, L1-absorbed), 9 coalesced plane writes.
// [962, 962+7500): x fp32 -> bf16.
__global__ __launch_bounds__(256) void prep_all(const float* __restrict__ x,
                                                const float* __restrict__ W,
                                                const void* __restrict__ adj_raw,
                                                unsigned short* __restrict__ wf,
                                                unsigned short* __restrict__ adjT,
                                                unsigned short* __restrict__ xh) {
  int blk = blockIdx.x;
  if (blk < 18) {
    int t = blk * 256 + threadIdx.x;
    if (t >= NS * 2 * 4 * 64) return;
    int lane = t & 63;
    int ct = (t >> 6) & 3;
    int kh = (t >> 8) & 1;
    int s  = t >> 9;
    int col = ct * 16 + (lane & 15);
    int kb  = s * 64 + kh * 32 + ((lane >> 4) << 3);
    u16x8 v;
#pragma unroll
    for (int j = 0; j < 8; ++j) v[j] = f2bf(W[col * 576 + kb + j]);
    *(u16x8*)&wf[t * 8] = v;
  } else if (blk < 18 + NB * 118) {
    int blk2 = blk - 18;
    int b = blk2 / 118, nb = blk2 - b * 118;
    int n = nb * 256 + threadIdx.x;
    if (n >= NPP) return;
    const int* a32 = (const int*)adj_raw;
    const long long* a64 = (const long long*)adj_raw;
    // int64 adj (values < 2^31) has all odd 32-bit words == 0.
    bool is64 = ((a32[1] | a32[3] | a32[5] | a32[7]) == 0);
    if (n >= NP) {
#pragma unroll
      for (int s = 0; s < NS; ++s) adjT[(size_t)(b * NS + s) * NPP + n] = 0;
      return;
    }
    size_t base = ((size_t)b * NP + n) * NS;
#pragma unroll
    for (int s = 0; s < NS; ++s) {
      long long vv = is64 ? a64[base + s] : (long long)a32[base + s];
      int vi = (int)vv;
      if ((unsigned)vi >= (unsigned)NP) vi = 0;
      adjT[(size_t)(b * NS + s) * NPP + n] = (unsigned short)vi;
    }
  } else {
    size_t i = ((size_t)(blk - 18 - NB * 118) * 256 + threadIdx.x) * 8;
    if (i >= (size_t)NB * NP * NC) return;
    float4 f0 = *(const float4*)(x + i);
    float4 f1 = *(const float4*)(x + i + 4);
    u16x8 v;
    v[0] = f2bf(f0.x); v[1] = f2bf(f0.y); v[2] = f2bf(f0.z); v[3] = f2bf(f0.w);
    v[4] = f2bf(f1.x); v[5] = f2bf(f1.y); v[6] = f2bf(f1.z); v[7] = f2bf(f1.w);
    *(u16x8*)&xh[i] = v;
  }
}

// Main: grid-stride over 128-row tiles (stride 64); block = 128 rows x 64 cols,
// 4 waves, 2 blocks/CU. Wave (wr,wc) = rows wr*64..+63, cols wc*32..+31.
// W resident in 144 VGPR/wave, loaded ONCE per block.
// A staged via global_load_lds into fragment layout. FOUR LDS buffers ->
// depth-2 completion: end of step S only requires stage(S+1); stage(S+2) and
// stage(S+3) stay in flight (WAITVM(8)). Gather latency budget = 2 full steps.
// Output stored non-temporally (don't evict x from the XCD L2).
__global__ __launch_bounds__(256, 2) void spiral_pipe(
    const unsigned short* __restrict__ adjT, const float* __restrict__ bias,
    const unsigned short* __restrict__ xh, const unsigned short* __restrict__ wf,
    float* __restrict__ out) {
  __shared__ __align__(16) char Alds[4][16384];   // [buf][frag = rt*2+kh][lane*16]

  const int tid = threadIdx.x;
  const int bid = blockIdx.x;
  const int b  = bid & 7;        // batch -> XCD pinning
  const int t0 = bid >> 3;       // first tile; stride 64
  const int w  = tid >> 6;
  const int l  = tid & 63;
  const int lr = l & 15;
  const int kq = l >> 4;
  const int wr = w >> 1;         // row-half 0/1 (64 rows)
  const int wc = w & 1;          // col-half 0/1 (32 cols)
  const unsigned wrofs = (unsigned)wr * 8192;

  const char* xb = (const char*)xh + (size_t)b * NP * 128 + kq * 16;
  float* outb = out + (size_t)b * NP * NO;
  const float bv0 = bias[wc * 32 + lr];
  const float bv1 = bias[wc * 32 + 16 + lr];

  unsigned abase[4];
#pragma unroll
  for (int bu = 0; bu < 4; ++bu) abase[bu] = lds_off(&Alds[bu][0]) + l * 16;

  // ---- W preload: once per block, asm (part of the hand-counted VMEM set) ----
  uint4 wreg[18][2];
#pragma unroll
  for (int sk = 0; sk < 18; ++sk)
#pragma unroll
    for (int j = 0; j < 2; ++j) {
      const char* wp = (const char*)wf + ((size_t)(sk * 4 + 2 * wc + j) * 64 + l) * 16;
      asm volatile("global_load_dwordx4 %0, %1, off" : "=v"(wreg[sk][j]) : "v"(wp));
    }

#define STAGE(S) {                                                        \
    unsigned pv = pidx[(S)];                                              \
    char* lb = &Alds[(S) % 4][0];                                         \
    unsigned r0 = pv & 0xFFFFu, r1 = pv >> 16;                            \
    const char* g0 = xb + (size_t)r0 * 128;                               \
    const char* g1 = xb + (size_t)r1 * 128;                               \
    gload_lds16(g0,      lb + (4 * w + 0) * 1024);                        \
    gload_lds16(g0 + 64, lb + (4 * w + 1) * 1024);                        \
    gload_lds16(g1,      lb + (4 * w + 2) * 1024);                        \
    gload_lds16(g1 + 64, lb + (4 * w + 3) * 1024);                        \
  }

#define WAITVM(N)                                                         \
    asm volatile("s_waitcnt vmcnt(" #N ")" ::: "memory");                 \
    __builtin_amdgcn_sched_barrier(0);

#define WAITLGN(N)                                                        \
    asm volatile("s_waitcnt lgkmcnt(" #N ")" ::: "memory");               \
    __builtin_amdgcn_sched_barrier(0);

#define RD(DST, OFF)                                                      \
    asm volatile("ds_read_b128 %0, %1 offset:" #OFF : "=v"(DST) : "v"(ab));

#define MF(A, WV, C) __builtin_amdgcn_mfma_f32_16x16x32_bf16(             \
    __builtin_bit_cast(bf16x8, (A)), __builtin_bit_cast(bf16x8, (WV)), (C), 0, 0, 0)

// 8 ds_reads (kh0 frags then kh1 frags of this wave's 4 row-tiles), then
// counted-lgkm paced MFMA pairs; acc dep distance = 8 MFMAs.
#define BODY(S) {                                                         \
    unsigned ab = abase[(S) % 4] + wrofs;                                 \
    uint4 f0, f1, f2, f3, f4, f5, f6, f7;                                 \
    RD(f0, 0)    RD(f1, 2048) RD(f2, 4096) RD(f3, 6144)                   \
    RD(f4, 1024) RD(f5, 3072) RD(f6, 5120) RD(f7, 7168)                   \
    WAITLGN(7) acc[0][0]=MF(f0,wreg[(S)*2][0],acc[0][0]); acc[0][1]=MF(f0,wreg[(S)*2][1],acc[0][1]); \
    WAITLGN(6) acc[1][0]=MF(f1,wreg[(S)*2][0],acc[1][0]); acc[1][1]=MF(f1,wreg[(S)*2][1],acc[1][1]); \
    WAITLGN(5) acc[2][0]=MF(f2,wreg[(S)*2][0],acc[2][0]); acc[2][1]=MF(f2,wreg[(S)*2][1],acc[2][1]); \
    WAITLGN(4) acc[3][0]=MF(f3,wreg[(S)*2][0],acc[3][0]); acc[3][1]=MF(f3,wreg[(S)*2][1],acc[3][1]); \
    WAITLGN(3) acc[0][0]=MF(f4,wreg[(S)*2+1][0],acc[0][0]); acc[0][1]=MF(f4,wreg[(S)*2+1][1],acc[0][1]); \
    WAITLGN(2) acc[1][0]=MF(f5,wreg[(S)*2+1][0],acc[1][0]); acc[1][1]=MF(f5,wreg[(S)*2+1][1],acc[1][1]); \
    WAITLGN(1) acc[2][0]=MF(f6,wreg[(S)*2+1][0],acc[2][0]); acc[2][1]=MF(f6,wreg[(S)*2+1][1],acc[2][1]); \
    WAITLGN(0) acc[3][0]=MF(f7,wreg[(S)*2+1][0],acc[3][0]); acc[3][1]=MF(f7,wreg[(S)*2+1][1],acc[3][1]); \
  }

// steady step S (0..5): stage S+3, compute S, require only stage(S+1) complete.
#define STEP_MID(S)                                                       \
    STAGE((S) + 3)                                                        \
    BODY(S)                                                               \
    WAITVM(8)                                                             \
    __builtin_amdgcn_s_barrier();

  for (int t = t0; t < NT; t += 64) {
    const int n0 = t * 128;

    // per-tile gather indices (plain loads; drained before the counted region)
    unsigned pidx[NS];
#pragma unroll
    for (int s = 0; s < NS; ++s) {
      const unsigned short* ap = adjT + (size_t)(b * NS + s) * NPP + n0 + 32 * w + lr;
      unsigned lo = ap[0], hi = ap[16];
      pidx[s] = lo | (hi << 16);
    }

    f32x4 acc[4][2] = {};

    // drain: W preload (first tile), prior-tile stores, pidx loads -> vmcnt exact
    asm volatile("s_waitcnt vmcnt(0)" ::: "memory");
    __builtin_amdgcn_sched_barrier(0);

    // prologue: stage bufs 0,1,2 (12 outstanding); require stage0 only.
    STAGE(0)
    STAGE(1)
    STAGE(2)
    WAITVM(8)
    __builtin_amdgcn_s_barrier();

    STEP_MID(0)
    STEP_MID(1)
    STEP_MID(2)
    STEP_MID(3)
    STEP_MID(4)
    STEP_MID(5)
    // tail: no more stages; ledger 8 -> 4 -> 0
    BODY(6)
    WAITVM(4)
    __builtin_amdgcn_s_barrier();
    BODY(7)
    WAITVM(0)
    __builtin_amdgcn_s_barrier();
    BODY(8)
    __builtin_amdgcn_s_barrier();  // protect bufs 0-2 from next tile's prologue

    // epilogue: bias + cheap ELU + mask; NON-TEMPORAL stores (don't evict x
    // from the XCD L2 that the gather depends on).
    // D layout: col = lane&15, row = (lane>>4)*4 + reg
#pragma unroll
    for (int rt = 0; rt < 4; ++rt) {
#pragma unroll
      for (int j = 0; j < 2; ++j) {
        const int col = wc * 32 + j * 16 + lr;
        const float bv = j ? bv1 : bv0;
#pragma unroll
        for (int r = 0; r < 4; ++r) {
          int n = n0 + wr * 64 + rt * 16 + kq * 4 + r;
          if (n < NP) {
            float v = acc[rt][j][r] + bv;
            v = (v > 0.f) ? v : (__expf(v) - 1.f);
            if (n == NP - 1) v = 0.f;
            __builtin_nontemporal_store(v, &outb[(size_t)n * NO + col]);
          }
        }
      }
    }
  }

#undef STEP_MID
#undef BODY
#undef MF
#undef RD
#undef WAITLGN
#undef WAITVM
#undef STAGE
}

// Fallback (workspace too small): fp32 direct path, compiler-scheduled.
__global__ __launch_bounds__(256, 3) void spiral_fb(
    const float* __restrict__ x, const void* __restrict__ adj_raw,
    const float* __restrict__ W, const float* __restrict__ bias,
    float* __restrict__ out) {
  const int tid = threadIdx.x;
  const int bid = blockIdx.x;
  const int b    = bid & 7;
  const int tile = bid >> 3;
  const int n0 = tile * 128;
  const int w  = tid >> 6;
  const int l  = tid & 63;
  const int lr = l & 15;
  const int kq = l >> 4;

  const int* a32 = (const int*)adj_raw;
  const long long* a64 = (const long long*)adj_raw;
  const bool is64 = ((a32[1] | a32[3] | a32[5] | a32[7]) == 0);

  int idx[2][NS];
#pragma unroll
  for (int rt = 0; rt < 2; ++rt) {
    int n = n0 + rt * 64 + w * 16 + lr;
    int nc = (n < NP) ? n : 0;
    size_t base = ((size_t)b * NP + nc) * NS;
#pragma unroll
    for (int s = 0; s < NS; ++s) {
      long long vv = is64 ? a64[base + s] : (long long)a32[base + s];
      int vi = (int)vv;
      idx[rt][s] = ((unsigned)vi < (unsigned)NP) ? vi : 0;
    }
  }

  f32x4 acc[2][4] = {};
  const float* xbf = x + (size_t)b * NP * NC + kq * 8;
#pragma unroll
  for (int s = 0; s < NS; ++s) {
    bf16x8 a[2][2];
#pragma unroll
    for (int rt = 0; rt < 2; ++rt) {
      const float* src = xbf + (size_t)idx[rt][s] * NC;
      float4 f0 = *(const float4*)src, f1 = *(const float4*)(src + 4);
      float4 g0 = *(const float4*)(src + 32), g1 = *(const float4*)(src + 36);
      u16x8 t0, t1;
      t0[0] = f2bf(f0.x); t0[1] = f2bf(f0.y); t0[2] = f2bf(f0.z); t0[3] = f2bf(f0.w);
      t0[4] = f2bf(f1.x); t0[5] = f2bf(f1.y); t0[6] = f2bf(f1.z); t0[7] = f2bf(f1.w);
      t1[0] = f2bf(g0.x); t1[1] = f2bf(g0.y); t1[2] = f2bf(g0.z); t1[3] = f2bf(g0.w);
      t1[4] = f2bf(g1.x); t1[5] = f2bf(g1.y); t1[6] = f2bf(g1.z); t1[7] = f2bf(g1.w);
      a[rt][0] = __builtin_bit_cast(bf16x8, t0);
      a[rt][1] = __builtin_bit_cast(bf16x8, t1);
    }
#pragma unroll
    for (int ct = 0; ct < 4; ++ct) {
#pragma unroll
      for (int kh = 0; kh < 2; ++kh) {
        int col = ct * 16 + lr;
        int kb  = s * 64 + kh * 32 + (kq << 3);
        const float4* wp = (const float4*)&W[col * 576 + kb];
        float4 w0 = wp[0], w1 = wp[1];
        u16x8 t;
        t[0] = f2bf(w0.x); t[1] = f2bf(w0.y); t[2] = f2bf(w0.z); t[3] = f2bf(w0.w);
        t[4] = f2bf(w1.x); t[5] = f2bf(w1.y); t[6] = f2bf(w1.z); t[7] = f2bf(w1.w);
        bf16x8 bf = __builtin_bit_cast(bf16x8, t);
        acc[0][ct] = __builtin_amdgcn_mfma_f32_16x16x32_bf16(a[0][kh], bf, acc[0][ct], 0, 0, 0);
        acc[1][ct] = __builtin_amdgcn_mfma_f32_16x16x32_bf16(a[1][kh], bf, acc[1][ct], 0, 0, 0);
      }
    }
  }

  const int orow = w * 16 + (kq << 2);
#pragma unroll
  for (int rt = 0; rt < 2; ++rt) {
#pragma unroll
    for (int ct = 0; ct < 4; ++ct) {
      int col = ct * 16 + lr;
      float bv = bias[col];
#pragma unroll
      for (int r = 0; r < 4; ++r) {
        int n = n0 + rt * 64 + orow + r;
        if (n < NP) {
          float v = acc[rt][ct][r] + bv;
          v = (v > 0.f) ? v : expm1f(v);
          if (n == NP - 1) v = 0.f;
          out[((size_t)b * NP + n) * NO + col] = v;
        }
      }
    }
  }
}

extern "C" void kernel_launch(void* const* d_in, const int* in_sizes, int n_in,
                              void* d_out, int out_size, void* d_ws, size_t ws_size,
                              hipStream_t stream) {
  const float* x    = (const float*)d_in[0];
  // d_in[1] = t_vertex (unused by the reference computation)
  const void*  adj  = d_in[2];
  const float* W    = (const float*)d_in[3];
  const float* bias = (const float*)d_in[4];
  float* out = (float*)d_out;

  const size_t wbytes = (size_t)NS * 2 * 4 * 64 * 8 * 2;            // 73728
  const size_t abytes = (size_t)NB * NS * NPP * 2;                  // 4,331,520
  const size_t xbytes = (size_t)NB * NP * NC * 2;                   // 30,720,000

  if (ws_size >= wbytes + abytes + xbytes) {
    unsigned short* wfrag = (unsigned short*)d_ws;
    unsigned short* adjT  = (unsigned short*)((char*)d_ws + wbytes);
    unsigned short* xh    = (unsigned short*)((char*)d_ws + wbytes + abytes);
    prep_all<<<18 + NB * 118 + 7500, 256, 0, stream>>>(x, W, adj, wfrag, adjT, xh);
    spiral_pipe<<<GBLK, 256, 0, stream>>>(adjT, bias, xh, wfrag, out);
  } else {
    const int nblk = ((NP + 127) / 128) * NB;
    spiral_fb<<<nblk, 256, 0, stream>>>(x, adj, W, bias, out);
  }
}